// Round 1
// baseline (327.186 us; speedup 1.0000x reference)
//
#include <hip/hip_runtime.h>

// BiAttention (BiDAF) fused kernels for MI355X / gfx950.
// B=32, C_L=2048, Q_L=256, D=256. Output G = [B][C_L][4*D] fp32.
//
// Strategy: S and c2q GEMMs via split-bf16 MFMA (3 terms: hh+hl+lh) for
// near-fp32 precision at ~2 PF rate. Softmax fused in-register. q2c path via
// fixed-offset exp (offset cancels in the ratio) + deterministic 2-stage sums.

#define B_   32
#define CL   2048
#define QL   256
#define DD   256
#define TC   32
#define NEGV -1.0e7f

typedef short bs8 __attribute__((ext_vector_type(8)));
typedef short bs4 __attribute__((ext_vector_type(4)));
typedef float fx4 __attribute__((ext_vector_type(4)));

__device__ __forceinline__ short f2bf(float x) {
    unsigned u = __float_as_uint(x);
    unsigned r = (u + 0x7fffu + ((u >> 16) & 1u)) >> 16;   // RNE
    return (short)r;
}
__device__ __forceinline__ float bf2f(short h) {
    return __uint_as_float(((unsigned)(unsigned short)h) << 16);
}

// ---------------------------------------------------------------- K0a: split q
// grid (4, 32): blockIdx.x = 64-row chunk, blockIdx.y = batch. 256 threads.
__global__ void k0_split(const float* __restrict__ q,
                         short* __restrict__ qh, short* __restrict__ ql,
                         short* __restrict__ qth, short* __restrict__ qtl) {
    __shared__ float lds[64][259];   // +3 pad: transpose-read 2-way max
    int t = threadIdx.x, lane = t & 63, w = t >> 6;
    int b = blockIdx.y, cn = blockIdx.x;
    for (int r = 0; r < 64; ++r)
        lds[r][t] = q[((size_t)b * QL + cn * 64 + r) * DD + t];
    __syncthreads();
    // natural layout [b][q][d]
    for (int r = 0; r < 64; ++r) {
        float v = lds[r][t];
        short h = f2bf(v);
        short lo = f2bf(v - bf2f(h));
        size_t o = ((size_t)b * QL + cn * 64 + r) * DD + t;
        qh[o] = h; ql[o] = lo;
    }
    // transposed layout [b][d][q]: wave w covers d = 64w..64w+63, lane = row
    for (int dd = 0; dd < 64; ++dd) {
        int d = w * 64 + dd;
        float v = lds[lane][d];
        short h = f2bf(v);
        short lo = f2bf(v - bf2f(h));
        size_t o = ((size_t)b * DD + d) * QL + cn * 64 + lane;
        qth[o] = h; qtl[o] = lo;
    }
}

// --------------------------------------------------------------- K0b: s_q dots
// grid 512 blocks x 256 thr: each wave reduces 4 q-rows (dot with w_q).
__global__ void k0_sq(const float* __restrict__ q, const float* __restrict__ W,
                      float* __restrict__ sq) {
    int t = threadIdx.x, lane = t & 63, w = t >> 6;
    int rowbase = blockIdx.x * 16 + w * 4;
    float4 wq = ((const float4*)(W + DD))[lane];
    for (int rr = 0; rr < 4; ++rr) {
        int row = rowbase + rr;   // flat over b*QL+q (8192 rows)
        float4 v = ((const float4*)q)[(size_t)row * 64 + lane];
        float d = v.x * wq.x + v.y * wq.y + v.z * wq.z + v.w * wq.w;
        for (int s = 32; s >= 1; s >>= 1) d += __shfl_xor(d, s, 64);
        if (lane == 0) sq[row] = d;
    }
}

// ------------------------------------------------------------------- K1: main
// grid (64, 32): blockIdx.x = c-tile (32 rows), blockIdx.y = batch. 256 thr.
__global__ __launch_bounds__(256) void k1(
        const float* __restrict__ ctx, const float* __restrict__ qmask,
        const float* __restrict__ W,
        const short* __restrict__ qh, const short* __restrict__ ql,
        const short* __restrict__ qth, const short* __restrict__ qtl,
        const float* __restrict__ sq, float* __restrict__ smax,
        float* __restrict__ G) {
    __shared__ union {
        short a[2][TC][264];   // [hi/lo][row][d], +8 pad -> 2-way max on b128
        float p[TC][268];      // attn, +12 pad -> 2-way max on b128
    } U;
    __shared__ float sq_l[QL], qm_l[QL], sc_l[TC];
    __shared__ float redA[2][2][TC], redB[2][2][TC];   // [wn][{a,u}][row]

    int t = threadIdx.x, lane = t & 63, wid = t >> 6;
    int wm = wid >> 1, wn = wid & 1;
    int l15 = lane & 15, lk = lane >> 4;
    int b = blockIdx.y, c0 = blockIdx.x * TC;

    sq_l[t] = sq[b * QL + t];
    qm_l[t] = qmask[b * QL + t];

    // Phase A: load c tile, write G part0, build split-bf16 A in LDS, s_c.
    float4 wcq = ((const float4*)W)[128 + lane];
    float4 wc  = ((const float4*)W)[lane];
    for (int rr = 0; rr < 8; ++rr) {
        int r = wid * 8 + rr;
        size_t grow = (size_t)b * CL + c0 + r;
        float4 v = ((const float4*)ctx)[grow * 64 + lane];
        ((float4*)G)[grow * 256 + lane] = v;   // part 0 = c
        float a0 = v.x * wcq.x, a1 = v.y * wcq.y, a2 = v.z * wcq.z, a3 = v.w * wcq.w;
        bs4 h, lo;
        h[0] = f2bf(a0); h[1] = f2bf(a1); h[2] = f2bf(a2); h[3] = f2bf(a3);
        lo[0] = f2bf(a0 - bf2f(h[0])); lo[1] = f2bf(a1 - bf2f(h[1]));
        lo[2] = f2bf(a2 - bf2f(h[2])); lo[3] = f2bf(a3 - bf2f(h[3]));
        *(bs4*)&U.a[0][r][4 * lane] = h;
        *(bs4*)&U.a[1][r][4 * lane] = lo;
        float d = v.x * wc.x + v.y * wc.y + v.z * wc.z + v.w * wc.w;
        for (int s = 32; s >= 1; s >>= 1) d += __shfl_xor(d, s, 64);
        if (lane == 0) sc_l[r] = d;
    }
    __syncthreads();

    // Phase B: S-GEMM. wave (wm,wn): rows 16wm..+15, q-cols 128wn..+127.
    fx4 acc[8];
#pragma unroll
    for (int i = 0; i < 8; ++i) acc[i] = (fx4)0.0f;
    const short* qhb = qh + (size_t)b * QL * DD;
    const short* qlb = ql + (size_t)b * QL * DD;
#pragma unroll
    for (int kk = 0; kk < 8; ++kk) {
        int k0 = kk * 32 + lk * 8;
        bs8 Ah = *(const bs8*)&U.a[0][16 * wm + l15][k0];
        bs8 Al = *(const bs8*)&U.a[1][16 * wm + l15][k0];
#pragma unroll
        for (int nt = 0; nt < 8; ++nt) {
            int qcol = 128 * wn + 16 * nt + l15;
            bs8 Bh = *(const bs8*)&qhb[(size_t)qcol * DD + k0];
            bs8 Bl = *(const bs8*)&qlb[(size_t)qcol * DD + k0];
            acc[nt] = __builtin_amdgcn_mfma_f32_16x16x32_bf16(Ah, Bh, acc[nt], 0, 0, 0);
            acc[nt] = __builtin_amdgcn_mfma_f32_16x16x32_bf16(Ah, Bl, acc[nt], 0, 0, 0);
            acc[nt] = __builtin_amdgcn_mfma_f32_16x16x32_bf16(Al, Bh, acc[nt], 0, 0, 0);
        }
    }

    // Softmax over q. D-frag: row = 16wm + 4*lk + j, col = 128wn + 16nt + l15.
    float mall[4], mu[4], scv[4];
#pragma unroll
    for (int j = 0; j < 4; ++j) {
        mall[j] = -3.0e38f; mu[j] = -3.0e38f;
        scv[j] = sc_l[16 * wm + 4 * lk + j];
    }
#pragma unroll
    for (int nt = 0; nt < 8; ++nt) {
        int col = 128 * wn + 16 * nt + l15;
        float sqv = sq_l[col], qmv = qm_l[col];
#pragma unroll
        for (int j = 0; j < 4; ++j) {
            float S = acc[nt][j] + scv[j] + sqv;
            float xm = S * qmv;                       // softmax input S*qm
            float ms = (qmv != 0.0f) ? S : NEGV;      // masked_S for s_max
            acc[nt][j] = xm;
            mall[j] = fmaxf(mall[j], xm);
            mu[j]   = fmaxf(mu[j], ms);
        }
    }
#pragma unroll
    for (int s = 1; s <= 8; s <<= 1)
#pragma unroll
        for (int j = 0; j < 4; ++j) {
            mall[j] = fmaxf(mall[j], __shfl_xor(mall[j], s, 64));
            mu[j]   = fmaxf(mu[j],   __shfl_xor(mu[j], s, 64));
        }
    if (l15 == 0)
#pragma unroll
        for (int j = 0; j < 4; ++j) {
            redA[wn][0][16 * wm + 4 * lk + j] = mall[j];
            redA[wn][1][16 * wm + 4 * lk + j] = mu[j];
        }
    __syncthreads();
#pragma unroll
    for (int j = 0; j < 4; ++j) {
        int row = 16 * wm + 4 * lk + j;
        mall[j] = fmaxf(redA[0][0][row], redA[1][0][row]);
        mu[j]   = fmaxf(redA[0][1][row], redA[1][1][row]);
    }
    if (wn == 0 && l15 == 0)
#pragma unroll
        for (int j = 0; j < 4; ++j)
            smax[(size_t)b * CL + c0 + 16 * wm + 4 * lk + j] = mu[j];

    float zal[4] = {0, 0, 0, 0}, zum[4] = {0, 0, 0, 0};
#pragma unroll
    for (int nt = 0; nt < 8; ++nt) {
        int col = 128 * wn + 16 * nt + l15;
        float qmv = qm_l[col];
#pragma unroll
        for (int j = 0; j < 4; ++j) {
            float e = __expf(acc[nt][j] - mall[j]);
            acc[nt][j] = e;
            zal[j] += e;
            zum[j] += e * qmv;
        }
    }
#pragma unroll
    for (int s = 1; s <= 8; s <<= 1)
#pragma unroll
        for (int j = 0; j < 4; ++j) {
            zal[j] += __shfl_xor(zal[j], s, 64);
            zum[j] += __shfl_xor(zum[j], s, 64);
        }
    if (l15 == 0)
#pragma unroll
        for (int j = 0; j < 4; ++j) {
            redB[wn][0][16 * wm + 4 * lk + j] = zal[j];
            redB[wn][1][16 * wm + 4 * lk + j] = zum[j];
        }
    __syncthreads();
    float inv[4];
#pragma unroll
    for (int j = 0; j < 4; ++j) {
        int row = 16 * wm + 4 * lk + j;
        float Za = redB[0][0][row] + redB[1][0][row];
        float Zu = redB[0][1][row] + redB[1][1][row];
        inv[j] = 1.0f / (Zu + 1e-13f * Za);   // exact reference denom
    }
    // Write P = attn into U.p (U.a dead: all waves past first barrier).
#pragma unroll
    for (int nt = 0; nt < 8; ++nt) {
        int col = 128 * wn + 16 * nt + l15;
        float qmv = qm_l[col];
#pragma unroll
        for (int j = 0; j < 4; ++j)
            U.p[16 * wm + 4 * lk + j][col] = acc[nt][j] * qmv * inv[j];
    }
    __syncthreads();

    // Phase C: c2q = P(32x256) @ q(256x256), split-bf16, B from qth/qtl.
    fx4 acc2[8];
#pragma unroll
    for (int i = 0; i < 8; ++i) acc2[i] = (fx4)0.0f;
    const short* qthb = qth + (size_t)b * DD * QL;
    const short* qtlb = qtl + (size_t)b * DD * QL;
#pragma unroll
    for (int kk = 0; kk < 8; ++kk) {
        int k0 = kk * 32 + lk * 8;
        const float* pr = &U.p[16 * wm + l15][k0];
        fx4 pa = *(const fx4*)pr;
        fx4 pb = *(const fx4*)(pr + 4);
        bs8 Ah, Al;
#pragma unroll
        for (int i = 0; i < 4; ++i) {
            short h = f2bf(pa[i]);  Ah[i] = h;     Al[i] = f2bf(pa[i] - bf2f(h));
            short h2 = f2bf(pb[i]); Ah[4 + i] = h2; Al[4 + i] = f2bf(pb[i] - bf2f(h2));
        }
#pragma unroll
        for (int nt = 0; nt < 8; ++nt) {
            int dcol = 128 * wn + 16 * nt + l15;
            bs8 Bh = *(const bs8*)&qthb[(size_t)dcol * QL + k0];
            bs8 Bl = *(const bs8*)&qtlb[(size_t)dcol * QL + k0];
            acc2[nt] = __builtin_amdgcn_mfma_f32_16x16x32_bf16(Ah, Bh, acc2[nt], 0, 0, 0);
            acc2[nt] = __builtin_amdgcn_mfma_f32_16x16x32_bf16(Ah, Bl, acc2[nt], 0, 0, 0);
            acc2[nt] = __builtin_amdgcn_mfma_f32_16x16x32_bf16(Al, Bh, acc2[nt], 0, 0, 0);
        }
    }
    // Phase D: epilogue — G parts 1 (c2q) and 2 (c*c2q).
#pragma unroll
    for (int nt = 0; nt < 8; ++nt)
#pragma unroll
        for (int j = 0; j < 4; ++j) {
            int row = 16 * wm + 4 * lk + j;
            int col = 128 * wn + 16 * nt + l15;
            size_t grow = (size_t)b * CL + c0 + row;
            float cval = ctx[grow * DD + col];
            float vv = acc2[nt][j];
            size_t gb = grow * 1024;
            G[gb + 256 + col] = vv;
            G[gb + 512 + col] = cval * vv;
        }
}

// ------------------------------------------------- K2a: e_c + partial Z sums
__global__ void k2a(const float* __restrict__ smax, const float* __restrict__ cmask,
                    float* __restrict__ ec, float* __restrict__ zup,
                    float* __restrict__ zap) {
    __shared__ float r1[4], r2[4];
    int t = threadIdx.x, lane = t & 63, w = t >> 6;
    int b = blockIdx.y;
    size_t c = (size_t)b * CL + blockIdx.x * 256 + t;
    float sm = smax[c], cm = cmask[c];
    float e  = (cm != 0.0f) ? __expf(sm - 32.0f) : 0.0f;       // exp(x-32)*cm
    float za = (cm != 0.0f) ? e : 1.2664166e-14f;              // exp(0-32)
    ec[c] = e;
    float s1 = e, s2 = za;
    for (int s = 32; s >= 1; s >>= 1) {
        s1 += __shfl_xor(s1, s, 64);
        s2 += __shfl_xor(s2, s, 64);
    }
    if (lane == 0) { r1[w] = s1; r2[w] = s2; }
    __syncthreads();
    if (t == 0) {
        zup[b * 8 + blockIdx.x] = r1[0] + r1[1] + r1[2] + r1[3];
        zap[b * 8 + blockIdx.x] = r2[0] + r2[1] + r2[2] + r2[3];
    }
}

// ------------------------------------------------- K2b: q2c partial reductions
__global__ void k2b(const float* __restrict__ ctx, const float* __restrict__ ec,
                    float* __restrict__ q2cp) {
    __shared__ float ew[128];
    int t = threadIdx.x;
    int b = blockIdx.y, ch = blockIdx.x;
    if (t < 128) ew[t] = ec[(size_t)b * CL + ch * 128 + t];
    __syncthreads();
    float acc = 0.0f;
    for (int r = 0; r < 128; ++r)
        acc = fmaf(ew[r], ctx[((size_t)b * CL + ch * 128 + r) * DD + t], acc);
    q2cp[((size_t)b * 16 + ch) * DD + t] = acc;
}

// ------------------------------------------------- K2c: finalize q2c (determ.)
__global__ void k2c(const float* __restrict__ q2cp, const float* __restrict__ zup,
                    const float* __restrict__ zap, float* __restrict__ q2c) {
    int t = threadIdx.x, b = blockIdx.x;
    float zu = 0.0f, za = 0.0f;
    for (int i = 0; i < 8; ++i) { zu += zup[b * 8 + i]; za += zap[b * 8 + i]; }
    float inv = 1.0f / (zu + 1e-13f * za);
    float s = 0.0f;
    for (int ch = 0; ch < 16; ++ch) s += q2cp[((size_t)b * 16 + ch) * DD + t];
    q2c[b * DD + t] = s * inv;
}

// ------------------------------------------------- K3: G part 3 = c * q2c
__global__ void k3(const float* __restrict__ ctx, const float* __restrict__ q2c,
                   float* __restrict__ G) {
    __shared__ float qv[256];
    int t = threadIdx.x;
    int b = blockIdx.y;
    qv[t] = q2c[b * DD + t];
    __syncthreads();
    int c0 = blockIdx.x * 16;
    for (int r = 0; r < 16; ++r) {
        size_t grow = (size_t)b * CL + c0 + r;
        float cval = ctx[grow * DD + t];
        G[grow * 1024 + 768 + t] = cval * qv[t];
    }
}

extern "C" void kernel_launch(void* const* d_in, const int* in_sizes, int n_in,
                              void* d_out, int out_size, void* d_ws, size_t ws_size,
                              hipStream_t stream) {
    const float* ctx   = (const float*)d_in[0];
    const float* cmask = (const float*)d_in[1];
    const float* q     = (const float*)d_in[2];
    const float* qmask = (const float*)d_in[3];
    const float* W     = (const float*)d_in[4];
    float* G = (float*)d_out;

    char* ws = (char*)d_ws;
    if (ws_size < (size_t)17893376) return;   // need ~17.1 MiB scratch
    short* qh  = (short*)(ws);
    short* ql  = (short*)(ws + 4194304);
    short* qth = (short*)(ws + 8388608);
    short* qtl = (short*)(ws + 12582912);
    float* sq   = (float*)(ws + 16777216);
    float* smax = (float*)(ws + 16809984);
    float* ec   = (float*)(ws + 17072128);
    float* zup  = (float*)(ws + 17334272);
    float* zap  = (float*)(ws + 17335296);
    float* q2cp = (float*)(ws + 17336320);
    float* q2cv = (float*)(ws + 17860608);

    k0_split<<<dim3(4, 32), dim3(256), 0, stream>>>(q, qh, ql, qth, qtl);
    k0_sq<<<dim3(512), dim3(256), 0, stream>>>(q, W, sq);
    k1<<<dim3(64, 32), dim3(256), 0, stream>>>(ctx, qmask, W, qh, ql, qth, qtl,
                                               sq, smax, G);
    k2a<<<dim3(8, 32), dim3(256), 0, stream>>>(smax, cmask, ec, zup, zap);
    k2b<<<dim3(16, 32), dim3(256), 0, stream>>>(ctx, ec, q2cp);
    k2c<<<dim3(32), dim3(256), 0, stream>>>(q2cp, zup, zap, q2cv);
    k3<<<dim3(128, 32), dim3(256), 0, stream>>>(ctx, q2cv, G);
}

// Round 2
// 243.144 us; speedup vs baseline: 1.3456x; 1.3456x over previous
//
#include <hip/hip_runtime.h>

// BiAttention (BiDAF) fused kernels for MI355X / gfx950.
// B=32, C_L=2048, Q_L=256, D=256. Output G = [B][C_L][4*D] fp32.
//
// Round 2: k1 restructured to m97-style LDS staging. B-operand chunks (K=32)
// loaded via global_load_lds (coalesced, width 16), fragments via
// ds_read_b128 with a rule-21 XOR sub-block swizzle (pre-swizzled global
// source + swizzled LDS read, linear LDS dest). P stored back into the A
// LDS buffer as split bf16 so phase C == phase B structurally. Epilogue via
// LDS -> coalesced float4 stores.

#define B_   32
#define CL   2048
#define QL   256
#define DD   256
#define TC   32
#define NEGV -1.0e7f

typedef short bs8 __attribute__((ext_vector_type(8)));
typedef short bs4 __attribute__((ext_vector_type(4)));
typedef float fx4 __attribute__((ext_vector_type(4)));

__device__ __forceinline__ short f2bf(float x) {
    unsigned u = __float_as_uint(x);
    unsigned r = (u + 0x7fffu + ((u >> 16) & 1u)) >> 16;   // RNE
    return (short)r;
}
__device__ __forceinline__ float bf2f(short h) {
    return __uint_as_float(((unsigned)(unsigned short)h) << 16);
}
__device__ __forceinline__ void gl16(const short* g, short* l) {
    __builtin_amdgcn_global_load_lds(
        (const __attribute__((address_space(1))) void*)g,
        (__attribute__((address_space(3))) void*)l, 16, 0, 0);
}

// ---------------------------------------------------------------- K0a: split q
// grid (4, 32): blockIdx.x = 64-row chunk, blockIdx.y = batch. 256 threads.
__global__ void k0_split(const float* __restrict__ q,
                         short* __restrict__ qh, short* __restrict__ ql,
                         short* __restrict__ qth, short* __restrict__ qtl) {
    __shared__ float lds[64][259];   // +3 pad
    int t = threadIdx.x, lane = t & 63, w = t >> 6;
    int b = blockIdx.y, cn = blockIdx.x;
    for (int r = 0; r < 64; ++r)
        lds[r][t] = q[((size_t)b * QL + cn * 64 + r) * DD + t];
    __syncthreads();
    // natural layout [b][q][d]
    for (int r = 0; r < 64; ++r) {
        float v = lds[r][t];
        short h = f2bf(v);
        short lo = f2bf(v - bf2f(h));
        size_t o = ((size_t)b * QL + cn * 64 + r) * DD + t;
        qh[o] = h; ql[o] = lo;
    }
    // transposed layout [b][d][q]
    for (int dd = 0; dd < 64; ++dd) {
        int d = w * 64 + dd;
        float v = lds[lane][d];
        short h = f2bf(v);
        short lo = f2bf(v - bf2f(h));
        size_t o = ((size_t)b * DD + d) * QL + cn * 64 + lane;
        qth[o] = h; qtl[o] = lo;
    }
}

// --------------------------------------------------------------- K0b: s_q dots
__global__ void k0_sq(const float* __restrict__ q, const float* __restrict__ W,
                      float* __restrict__ sq) {
    int t = threadIdx.x, lane = t & 63, w = t >> 6;
    int rowbase = blockIdx.x * 16 + w * 4;
    float4 wq = ((const float4*)(W + DD))[lane];
    for (int rr = 0; rr < 4; ++rr) {
        int row = rowbase + rr;
        float4 v = ((const float4*)q)[(size_t)row * 64 + lane];
        float d = v.x * wq.x + v.y * wq.y + v.z * wq.z + v.w * wq.w;
        for (int s = 32; s >= 1; s >>= 1) d += __shfl_xor(d, s, 64);
        if (lane == 0) sq[row] = d;
    }
}

// ------------------------------------------------------------------- K1: main
// grid (64, 32): blockIdx.x = c-tile (32 rows), blockIdx.y = batch. 256 thr.
__global__ __launch_bounds__(256) void k1(
        const float* __restrict__ ctx, const float* __restrict__ qmask,
        const float* __restrict__ W,
        const short* __restrict__ qh, const short* __restrict__ ql,
        const short* __restrict__ qth, const short* __restrict__ qtl,
        const float* __restrict__ sq, float* __restrict__ smax,
        float* __restrict__ G) {
    __shared__ short A[2][TC][264];          // A hi/lo, then P hi/lo (33.8 KB)
    union BufU { short bb[2][256][32]; float pout[TC][260]; };
    __shared__ BufU UB;                      // B chunks / epilogue (33.3 KB)
    __shared__ float sq_l[QL], qm_l[QL], sc_l[TC];
    __shared__ float redA[2][2][TC], redB[2][2][TC];

    int t = threadIdx.x, lane = t & 63, wid = t >> 6;
    int wm = wid >> 1, wn = wid & 1;
    int l15 = lane & 15, lk = lane >> 4;
    int r4 = lane >> 2, c4 = lane & 3;
    int b = blockIdx.y, c0 = blockIdx.x * TC;

    sq_l[t] = sq[b * QL + t];
    qm_l[t] = qmask[b * QL + t];

    // Phase A: load c tile, write G part0, build split-bf16 A in LDS, s_c.
    float4 wcq = ((const float4*)W)[128 + lane];
    float4 wc  = ((const float4*)W)[lane];
    for (int rr = 0; rr < 8; ++rr) {
        int r = wid * 8 + rr;
        size_t grow = (size_t)b * CL + c0 + r;
        float4 v = ((const float4*)ctx)[grow * 64 + lane];
        ((float4*)G)[grow * 256 + lane] = v;   // part 0 = c
        float a0 = v.x * wcq.x, a1 = v.y * wcq.y, a2 = v.z * wcq.z, a3 = v.w * wcq.w;
        bs4 h, lo;
        h[0] = f2bf(a0); h[1] = f2bf(a1); h[2] = f2bf(a2); h[3] = f2bf(a3);
        lo[0] = f2bf(a0 - bf2f(h[0])); lo[1] = f2bf(a1 - bf2f(h[1]));
        lo[2] = f2bf(a2 - bf2f(h[2])); lo[3] = f2bf(a3 - bf2f(h[3]));
        *(bs4*)&A[0][r][4 * lane] = h;
        *(bs4*)&A[1][r][4 * lane] = lo;
        float d = v.x * wc.x + v.y * wc.y + v.z * wc.z + v.w * wc.w;
        for (int s = 32; s >= 1; s >>= 1) d += __shfl_xor(d, s, 64);
        if (lane == 0) sc_l[r] = d;
    }

    // Phase B: S-GEMM, 8 chunks of K=32, B staged in LDS via global_load_lds.
    fx4 acc[8];
#pragma unroll
    for (int i = 0; i < 8; ++i) acc[i] = (fx4)0.0f;
    const short* qhb = qh + (size_t)b * QL * DD;
    const short* qlb = ql + (size_t)b * QL * DD;
    for (int kk = 0; kk < 8; ++kk) {
        __syncthreads();                        // prev chunk consumed / A ready
#pragma unroll
        for (int i = 0; i < 4; ++i) {
            int qb = 64 * wid + 16 * i;
            int row = qb + r4;
            int cs = (c4 ^ ((row >> 1) & 3)) * 8;      // source pre-swizzle
            gl16(qhb + (size_t)row * DD + kk * 32 + cs, &UB.bb[0][qb][0]);
            gl16(qlb + (size_t)row * DD + kk * 32 + cs, &UB.bb[1][qb][0]);
        }
        asm volatile("s_waitcnt vmcnt(0)" ::: "memory");
        __syncthreads();
        bs8 Ah = *(const bs8*)&A[0][16 * wm + l15][kk * 32 + lk * 8];
        bs8 Al = *(const bs8*)&A[1][16 * wm + l15][kk * 32 + lk * 8];
#pragma unroll
        for (int nt = 0; nt < 8; ++nt) {
            int col = 128 * wn + 16 * nt + l15;
            int ko = (lk ^ ((col >> 1) & 3)) * 8;      // swizzled read
            bs8 Bh = *(const bs8*)&UB.bb[0][col][ko];
            bs8 Bl = *(const bs8*)&UB.bb[1][col][ko];
            acc[nt] = __builtin_amdgcn_mfma_f32_16x16x32_bf16(Ah, Bh, acc[nt], 0, 0, 0);
            acc[nt] = __builtin_amdgcn_mfma_f32_16x16x32_bf16(Ah, Bl, acc[nt], 0, 0, 0);
            acc[nt] = __builtin_amdgcn_mfma_f32_16x16x32_bf16(Al, Bh, acc[nt], 0, 0, 0);
        }
    }

    // Softmax over q. D-frag: row = 16wm + 4*lk + j, col = 128wn + 16nt + l15.
    float mall[4], mu[4], scv[4];
#pragma unroll
    for (int j = 0; j < 4; ++j) {
        mall[j] = -3.0e38f; mu[j] = -3.0e38f;
        scv[j] = sc_l[16 * wm + 4 * lk + j];
    }
#pragma unroll
    for (int nt = 0; nt < 8; ++nt) {
        int col = 128 * wn + 16 * nt + l15;
        float sqv = sq_l[col], qmv = qm_l[col];
#pragma unroll
        for (int j = 0; j < 4; ++j) {
            float S = acc[nt][j] + scv[j] + sqv;
            float xm = S * qmv;
            float ms = (qmv != 0.0f) ? S : NEGV;
            acc[nt][j] = xm;
            mall[j] = fmaxf(mall[j], xm);
            mu[j]   = fmaxf(mu[j], ms);
        }
    }
#pragma unroll
    for (int s = 1; s <= 8; s <<= 1)
#pragma unroll
        for (int j = 0; j < 4; ++j) {
            mall[j] = fmaxf(mall[j], __shfl_xor(mall[j], s, 64));
            mu[j]   = fmaxf(mu[j],   __shfl_xor(mu[j], s, 64));
        }
    if (l15 == 0)
#pragma unroll
        for (int j = 0; j < 4; ++j) {
            redA[wn][0][16 * wm + 4 * lk + j] = mall[j];
            redA[wn][1][16 * wm + 4 * lk + j] = mu[j];
        }
    __syncthreads();
#pragma unroll
    for (int j = 0; j < 4; ++j) {
        int row = 16 * wm + 4 * lk + j;
        mall[j] = fmaxf(redA[0][0][row], redA[1][0][row]);
        mu[j]   = fmaxf(redA[0][1][row], redA[1][1][row]);
    }
    if (wn == 0 && l15 == 0)
#pragma unroll
        for (int j = 0; j < 4; ++j)
            smax[(size_t)b * CL + c0 + 16 * wm + 4 * lk + j] = mu[j];

    float zal[4] = {0, 0, 0, 0}, zum[4] = {0, 0, 0, 0};
#pragma unroll
    for (int nt = 0; nt < 8; ++nt) {
        int col = 128 * wn + 16 * nt + l15;
        float qmv = qm_l[col];
#pragma unroll
        for (int j = 0; j < 4; ++j) {
            float e = __expf(acc[nt][j] - mall[j]);
            acc[nt][j] = e;
            zal[j] += e;
            zum[j] += e * qmv;
        }
    }
#pragma unroll
    for (int s = 1; s <= 8; s <<= 1)
#pragma unroll
        for (int j = 0; j < 4; ++j) {
            zal[j] += __shfl_xor(zal[j], s, 64);
            zum[j] += __shfl_xor(zum[j], s, 64);
        }
    if (l15 == 0)
#pragma unroll
        for (int j = 0; j < 4; ++j) {
            redB[wn][0][16 * wm + 4 * lk + j] = zal[j];
            redB[wn][1][16 * wm + 4 * lk + j] = zum[j];
        }
    __syncthreads();
    float inv[4];
#pragma unroll
    for (int j = 0; j < 4; ++j) {
        int row = 16 * wm + 4 * lk + j;
        float Za = redB[0][0][row] + redB[1][0][row];
        float Zu = redB[0][1][row] + redB[1][1][row];
        inv[j] = 1.0f / (Zu + 1e-13f * Za);
    }
    // P (split bf16) overwrites A: same fragment path for phase C.
#pragma unroll
    for (int nt = 0; nt < 8; ++nt) {
        int col = 128 * wn + 16 * nt + l15;
        float qmv = qm_l[col];
#pragma unroll
        for (int j = 0; j < 4; ++j) {
            int row = 16 * wm + 4 * lk + j;
            float p = acc[nt][j] * qmv * inv[j];
            short h = f2bf(p);
            A[0][row][col] = h;
            A[1][row][col] = f2bf(p - bf2f(h));
        }
    }

    // Phase C: c2q = P(32x256) @ q^T-layout(256x256), 8 chunks of K=32.
    fx4 acc2[8];
#pragma unroll
    for (int i = 0; i < 8; ++i) acc2[i] = (fx4)0.0f;
    const short* qthb = qth + (size_t)b * DD * QL;
    const short* qtlb = qtl + (size_t)b * DD * QL;
    for (int kk = 0; kk < 8; ++kk) {
        __syncthreads();                        // P written / prev chunk done
#pragma unroll
        for (int i = 0; i < 4; ++i) {
            int qb = 64 * wid + 16 * i;
            int row = qb + r4;
            int cs = (c4 ^ ((row >> 1) & 3)) * 8;
            gl16(qthb + (size_t)row * QL + kk * 32 + cs, &UB.bb[0][qb][0]);
            gl16(qtlb + (size_t)row * QL + kk * 32 + cs, &UB.bb[1][qb][0]);
        }
        asm volatile("s_waitcnt vmcnt(0)" ::: "memory");
        __syncthreads();
        bs8 Ph = *(const bs8*)&A[0][16 * wm + l15][kk * 32 + lk * 8];
        bs8 Pl = *(const bs8*)&A[1][16 * wm + l15][kk * 32 + lk * 8];
#pragma unroll
        for (int nt = 0; nt < 8; ++nt) {
            int col = 128 * wn + 16 * nt + l15;
            int ko = (lk ^ ((col >> 1) & 3)) * 8;
            bs8 Bh = *(const bs8*)&UB.bb[0][col][ko];
            bs8 Bl = *(const bs8*)&UB.bb[1][col][ko];
            acc2[nt] = __builtin_amdgcn_mfma_f32_16x16x32_bf16(Ph, Bh, acc2[nt], 0, 0, 0);
            acc2[nt] = __builtin_amdgcn_mfma_f32_16x16x32_bf16(Ph, Bl, acc2[nt], 0, 0, 0);
            acc2[nt] = __builtin_amdgcn_mfma_f32_16x16x32_bf16(Pl, Bh, acc2[nt], 0, 0, 0);
        }
    }

    // Epilogue: c2q -> LDS -> coalesced float4 stores of G parts 1 and 2.
    __syncthreads();                            // last B-chunk reads done
#pragma unroll
    for (int nt = 0; nt < 8; ++nt)
#pragma unroll
        for (int j = 0; j < 4; ++j)
            UB.pout[16 * wm + 4 * lk + j][128 * wn + 16 * nt + l15] = acc2[nt][j];
    __syncthreads();
    for (int rr = 0; rr < 8; ++rr) {
        int r = wid * 8 + rr;
        size_t grow = (size_t)b * CL + c0 + r;
        float4 cv = ((const float4*)ctx)[grow * 64 + lane];
        float4 vv = *(const float4*)&UB.pout[r][4 * lane];
        ((float4*)G)[grow * 256 + 64 + lane] = vv;
        float4 p2;
        p2.x = cv.x * vv.x; p2.y = cv.y * vv.y;
        p2.z = cv.z * vv.z; p2.w = cv.w * vv.w;
        ((float4*)G)[grow * 256 + 128 + lane] = p2;
    }
}

// ------------------------------------------------- K2a: e_c + partial Z sums
__global__ void k2a(const float* __restrict__ smax, const float* __restrict__ cmask,
                    float* __restrict__ ec, float* __restrict__ zup,
                    float* __restrict__ zap) {
    __shared__ float r1[4], r2[4];
    int t = threadIdx.x, lane = t & 63, w = t >> 6;
    int b = blockIdx.y;
    size_t c = (size_t)b * CL + blockIdx.x * 256 + t;
    float sm = smax[c], cm = cmask[c];
    float e  = (cm != 0.0f) ? __expf(sm - 32.0f) : 0.0f;
    float za = (cm != 0.0f) ? e : 1.2664166e-14f;              // exp(-32)
    ec[c] = e;
    float s1 = e, s2 = za;
    for (int s = 32; s >= 1; s >>= 1) {
        s1 += __shfl_xor(s1, s, 64);
        s2 += __shfl_xor(s2, s, 64);
    }
    if (lane == 0) { r1[w] = s1; r2[w] = s2; }
    __syncthreads();
    if (t == 0) {
        zup[b * 8 + blockIdx.x] = r1[0] + r1[1] + r1[2] + r1[3];
        zap[b * 8 + blockIdx.x] = r2[0] + r2[1] + r2[2] + r2[3];
    }
}

// ------------------------------------------------- K2b: q2c partial reductions
__global__ void k2b(const float* __restrict__ ctx, const float* __restrict__ ec,
                    float* __restrict__ q2cp) {
    __shared__ float ew[128];
    int t = threadIdx.x;
    int b = blockIdx.y, ch = blockIdx.x;
    if (t < 128) ew[t] = ec[(size_t)b * CL + ch * 128 + t];
    __syncthreads();
    float acc = 0.0f;
    for (int r = 0; r < 128; ++r)
        acc = fmaf(ew[r], ctx[((size_t)b * CL + ch * 128 + r) * DD + t], acc);
    q2cp[((size_t)b * 16 + ch) * DD + t] = acc;
}

// ------------------------------------------------- K2c: finalize q2c (determ.)
__global__ void k2c(const float* __restrict__ q2cp, const float* __restrict__ zup,
                    const float* __restrict__ zap, float* __restrict__ q2c) {
    int t = threadIdx.x, b = blockIdx.x;
    float zu = 0.0f, za = 0.0f;
    for (int i = 0; i < 8; ++i) { zu += zup[b * 8 + i]; za += zap[b * 8 + i]; }
    float inv = 1.0f / (zu + 1e-13f * za);
    float s = 0.0f;
    for (int ch = 0; ch < 16; ++ch) s += q2cp[((size_t)b * 16 + ch) * DD + t];
    q2c[b * DD + t] = s * inv;
}

// ------------------------------------------------- K3: G part 3 = c * q2c
__global__ void k3(const float* __restrict__ ctx, const float* __restrict__ q2c,
                   float* __restrict__ G) {
    __shared__ float4 qv[64];
    int t = threadIdx.x, lane = t & 63, w = t >> 6;
    int b = blockIdx.y;
    if (t < 64) qv[t] = ((const float4*)q2c)[b * 64 + t];
    __syncthreads();
    int c0 = blockIdx.x * 16;
    float4 q4 = qv[lane];
    for (int r = w; r < 16; r += 4) {
        size_t grow = (size_t)b * CL + c0 + r;
        float4 cv = ((const float4*)ctx)[grow * 64 + lane];
        float4 o;
        o.x = cv.x * q4.x; o.y = cv.y * q4.y;
        o.z = cv.z * q4.z; o.w = cv.w * q4.w;
        ((float4*)G)[grow * 256 + 192 + lane] = o;
    }
}

extern "C" void kernel_launch(void* const* d_in, const int* in_sizes, int n_in,
                              void* d_out, int out_size, void* d_ws, size_t ws_size,
                              hipStream_t stream) {
    const float* ctx   = (const float*)d_in[0];
    const float* cmask = (const float*)d_in[1];
    const float* q     = (const float*)d_in[2];
    const float* qmask = (const float*)d_in[3];
    const float* W     = (const float*)d_in[4];
    float* G = (float*)d_out;

    char* ws = (char*)d_ws;
    if (ws_size < (size_t)17893376) return;
    short* qh  = (short*)(ws);
    short* ql  = (short*)(ws + 4194304);
    short* qth = (short*)(ws + 8388608);
    short* qtl = (short*)(ws + 12582912);
    float* sq   = (float*)(ws + 16777216);
    float* smax = (float*)(ws + 16809984);
    float* ec   = (float*)(ws + 17072128);
    float* zup  = (float*)(ws + 17334272);
    float* zap  = (float*)(ws + 17335296);
    float* q2cp = (float*)(ws + 17336320);
    float* q2cv = (float*)(ws + 17860608);

    k0_split<<<dim3(4, 32), dim3(256), 0, stream>>>(q, qh, ql, qth, qtl);
    k0_sq<<<dim3(512), dim3(256), 0, stream>>>(q, W, sq);
    k1<<<dim3(64, 32), dim3(256), 0, stream>>>(ctx, qmask, W, qh, ql, qth, qtl,
                                               sq, smax, G);
    k2a<<<dim3(8, 32), dim3(256), 0, stream>>>(smax, cmask, ec, zup, zap);
    k2b<<<dim3(16, 32), dim3(256), 0, stream>>>(ctx, ec, q2cp);
    k2c<<<dim3(32), dim3(256), 0, stream>>>(q2cp, zup, zap, q2cv);
    k3<<<dim3(128, 32), dim3(256), 0, stream>>>(ctx, q2cv, G);
}